// Round 2
// baseline (281.984 us; speedup 1.0000x reference)
//
#include <hip/hip_runtime.h>
#include <hip/hip_bf16.h>

// Problem constants (from reference)
constexpr int EDGES  = 250000;
constexpr int EMB    = 64;
constexpr int CNUM   = 128;
constexpr int NSTU   = 10000;
constexpr int NITEM  = 50000;
constexpr int NCONC  = 2048;

// workspace layout (fp32): SP | IP | CS | CI | flag
constexpr size_t SP_OFF = 0;
constexpr size_t IP_OFF = SP_OFF + (size_t)NSTU  * CNUM;
constexpr size_t CS_OFF = IP_OFF + (size_t)NITEM * CNUM;
constexpr size_t CI_OFF = CS_OFF + (size_t)NCONC * CNUM;
constexpr size_t WS_FLOATS = CI_OFF + (size_t)NCONC * CNUM;  // 8,204,288

__device__ __forceinline__ float bf_lo(unsigned u) {
    union { unsigned u; float f; } c; c.u = u << 16; return c.f;
}
__device__ __forceinline__ float bf_hi(unsigned u) {
    union { unsigned u; float f; } c; c.u = u & 0xffff0000u; return c.f;
}
__device__ __forceinline__ float sigm(float x) {
    float e = __builtin_amdgcn_exp2f(x * -1.44269504088896340736f);
    return __builtin_amdgcn_rcpf(1.0f + e);
}

// ---- dtype detector -------------------------------------------------------
// Inspect raw 32-bit words of stu_fusion. If storage is fp32 (IEEE floats of
// N(0,1) data), the LOW 16 bits reinterpreted as bf16 have ~uniform random
// exponents -> mostly exotic magnitudes. If storage is bf16 pairs, every half
// is a sane N(0,1) value. flag: 1 = fp32, 0 = bf16.
__global__ void detect_kernel(const unsigned* __restrict__ raw,
                              int* __restrict__ flag) {
    __shared__ int cnt;
    if (threadIdx.x == 0) cnt = 0;
    __syncthreads();
    int local = 0;
    for (int i = threadIdx.x; i < 4096; i += 256) {
        float a = fabsf(bf_lo(raw[i]));
        if (!(a <= 1e3f) || (a > 0.f && a < 1e-10f)) local++;  // catches NaN/Inf too
    }
    atomicAdd(&cnt, local);
    __syncthreads();
    if (threadIdx.x == 0) *flag = (cnt > 64) ? 1 : 0;
}

// ---- projection: out[r,c] = sum_j F[r,j] * W[c, col_off+j], j in [0,EMB) ---
// W row (64 values) cached per-thread in VGPRs; 2 rows/block-iter (256 thr).
template <bool FP32>
__device__ __forceinline__ void proj_body(const void* __restrict__ Fv, int rows,
                                          const void* __restrict__ Wv, int col_off,
                                          float* __restrict__ out) {
    const int tid  = threadIdx.x;
    const int c    = tid & (CNUM - 1);
    const int half = tid >> 7;  // 0/1

    float w[EMB];
    if (FP32) {
        const float4* Wr = (const float4*)((const float*)Wv + c * (2 * EMB) + col_off);
#pragma unroll
        for (int j = 0; j < 16; ++j) {
            float4 u = Wr[j];
            w[4*j+0] = u.x; w[4*j+1] = u.y; w[4*j+2] = u.z; w[4*j+3] = u.w;
        }
    } else {
        const uint4* Wr = (const uint4*)((const __hip_bfloat16*)Wv + c * (2 * EMB) + col_off);
#pragma unroll
        for (int j = 0; j < 8; ++j) {
            uint4 u = Wr[j];
            w[8*j+0] = bf_lo(u.x); w[8*j+1] = bf_hi(u.x);
            w[8*j+2] = bf_lo(u.y); w[8*j+3] = bf_hi(u.y);
            w[8*j+4] = bf_lo(u.z); w[8*j+5] = bf_hi(u.z);
            w[8*j+6] = bf_lo(u.w); w[8*j+7] = bf_hi(u.w);
        }
    }

    for (int r = blockIdx.x * 2 + half; r < rows; r += gridDim.x * 2) {
        float acc = 0.f;
        if (FP32) {
            const float4* Fr = (const float4*)((const float*)Fv + r * EMB);
#pragma unroll
            for (int j = 0; j < 16; ++j) {
                float4 u = Fr[j];
                acc += u.x * w[4*j+0] + u.y * w[4*j+1] + u.z * w[4*j+2] + u.w * w[4*j+3];
            }
        } else {
            const uint4* Fr = (const uint4*)((const __hip_bfloat16*)Fv + r * EMB);
#pragma unroll
            for (int j = 0; j < 8; ++j) {
                uint4 u = Fr[j];
                acc += bf_lo(u.x) * w[8*j+0] + bf_hi(u.x) * w[8*j+1]
                     + bf_lo(u.y) * w[8*j+2] + bf_hi(u.y) * w[8*j+3]
                     + bf_lo(u.z) * w[8*j+4] + bf_hi(u.z) * w[8*j+5]
                     + bf_lo(u.w) * w[8*j+6] + bf_hi(u.w) * w[8*j+7];
            }
        }
        out[r * CNUM + c] = acc;  // coalesced across the 128 lanes of c
    }
}

__global__ __launch_bounds__(256) void proj_kernel(
        const void* __restrict__ F, int rows,
        const void* __restrict__ W, int col_off,
        float* __restrict__ out, const int* __restrict__ flag) {
    if (*flag) proj_body<true >(F, rows, W, col_off, out);
    else       proj_body<false>(F, rows, W, col_off, out);
}

// ---- edge phase: one 64-lane wave per edge; lane l owns concepts 2l,2l+1 ---
__global__ __launch_bounds__(256) void edge_kernel(
        const int*  __restrict__ stu_idx,
        const int*  __restrict__ item_idx,
        const int4* __restrict__ conc_idx,   // (EDGES, 4) as int4
        const float* __restrict__ SP,        // (NSTU, 128)
        const float* __restrict__ IP,        // (NITEM, 128)
        const float* __restrict__ CS,        // (NCONC, 128)
        const float* __restrict__ CI,        // (NCONC, 128)
        const void* __restrict__ w_pred,
        const void* __restrict__ b_pred,
        void* __restrict__ out,
        const int* __restrict__ flag) {
    const int wid  = (blockIdx.x * blockDim.x + threadIdx.x) >> 6;
    const int lane = threadIdx.x & 63;
    if (wid >= EDGES) return;
    const int e = wid;
    const bool fp32 = (*flag != 0);

    const int s  = stu_idx[e];    // wave-uniform
    const int it = item_idx[e];   // wave-uniform
    const int4 c4 = conc_idx[e];  // wave-uniform, one 16B load

    const float2 sp = ((const float2*)(SP + (size_t)s  * CNUM))[lane];
    const float2 ip = ((const float2*)(IP + (size_t)it * CNUM))[lane];

    float wx, wy, b;
    if (fp32) {
        float2 w = ((const float2*)w_pred)[lane];
        wx = w.x; wy = w.y;
        b = ((const float*)b_pred)[0];
    } else {
        const __hip_bfloat16* wp = (const __hip_bfloat16*)w_pred;
        wx = __bfloat162float(wp[2 * lane]);
        wy = __bfloat162float(wp[2 * lane + 1]);
        b = __bfloat162float(((const __hip_bfloat16*)b_pred)[0]);
    }

    const int cc[4] = {c4.x, c4.y, c4.z, c4.w};
    float p[4];
#pragma unroll
    for (int k = 0; k < 4; ++k) {
        const float2 cs = ((const float2*)(CS + (size_t)cc[k] * CNUM))[lane];
        const float2 cv = ((const float2*)(CI + (size_t)cc[k] * CNUM))[lane];
        float d0 = sigm(sp.x + cs.x) - sigm(ip.x + cv.x);
        float d1 = sigm(sp.y + cs.y) - sigm(ip.y + cv.y);
        p[k] = d0 * wx + d1 * wy;
    }

#pragma unroll
    for (int off = 32; off > 0; off >>= 1) {
        p[0] += __shfl_xor(p[0], off, 64);
        p[1] += __shfl_xor(p[1], off, 64);
        p[2] += __shfl_xor(p[2], off, 64);
        p[3] += __shfl_xor(p[3], off, 64);
    }

    if (lane == 0) {
        float r = 0.25f * (sigm(p[0] + b) + sigm(p[1] + b) +
                           sigm(p[2] + b) + sigm(p[3] + b));
        if (fp32) ((float*)out)[e] = r;
        else      ((__hip_bfloat16*)out)[e] = __float2bfloat16(r);
    }
}

extern "C" void kernel_launch(void* const* d_in, const int* in_sizes, int n_in,
                              void* d_out, int out_size, void* d_ws, size_t ws_size,
                              hipStream_t stream) {
    const int* stu_idx  = (const int*)d_in[0];
    const int* item_idx = (const int*)d_in[1];
    const int* conc_idx = (const int*)d_in[2];
    const void* stu_fusion     = d_in[3];
    const void* item_fusion    = d_in[4];
    const void* concept_fusion = d_in[5];
    const void* W_stu          = d_in[6];
    const void* W_item         = d_in[7];
    const void* w_pred         = d_in[8];
    const void* b_pred         = d_in[9];

    float* SP = (float*)d_ws + SP_OFF;
    float* IP = (float*)d_ws + IP_OFF;
    float* CS = (float*)d_ws + CS_OFF;
    float* CI = (float*)d_ws + CI_OFF;
    int* flag = (int*)((float*)d_ws + WS_FLOATS);

    detect_kernel<<<1, 256, 0, stream>>>((const unsigned*)stu_fusion, flag);

    proj_kernel<<<1024, 256, 0, stream>>>(stu_fusion,     NSTU,  W_stu,  0,   SP, flag);
    proj_kernel<<<1024, 256, 0, stream>>>(item_fusion,    NITEM, W_item, 0,   IP, flag);
    proj_kernel<<<1024, 256, 0, stream>>>(concept_fusion, NCONC, W_stu,  EMB, CS, flag);
    proj_kernel<<<1024, 256, 0, stream>>>(concept_fusion, NCONC, W_item, EMB, CI, flag);

    // 4 waves per 256-block, 1 edge per wave; 62500 * 4 = 250000 exactly
    edge_kernel<<<EDGES / 4, 256, 0, stream>>>(
        stu_idx, item_idx, (const int4*)conc_idx,
        SP, IP, CS, CI, w_pred, b_pred, d_out, flag);
}

// Round 3
// 260.672 us; speedup vs baseline: 1.0818x; 1.0818x over previous
//
#include <hip/hip_runtime.h>
#include <hip/hip_bf16.h>

// Problem constants (from reference). All float tensors are fp32 (proven R1/R2:
// bf16 interpretation NaN'd, fp32 path validated with absmax = bf16 quantization
// floor of the expected values). Output is fp32.
constexpr int EDGES = 250000;
constexpr int EMB   = 64;
constexpr int CNUM  = 128;
constexpr int NSTU  = 10000;
constexpr int NITEM = 50000;
constexpr int NCONC = 2048;

// workspace layout (fp32): SP | IP | CS | CI
constexpr size_t SP_OFF = 0;
constexpr size_t IP_OFF = SP_OFF + (size_t)NSTU  * CNUM;
constexpr size_t CS_OFF = IP_OFF + (size_t)NITEM * CNUM;
constexpr size_t CI_OFF = CS_OFF + (size_t)NCONC * CNUM;

// proj_all block segmentation
constexpr int STU_BLKS  = 256;
constexpr int ITEM_BLKS = 1024;
constexpr int CONC_BLKS = 64;
constexpr int TOTAL_BLKS = STU_BLKS + ITEM_BLKS + CONC_BLKS;

__device__ __forceinline__ float sigm(float x) {
    float e = __builtin_amdgcn_exp2f(x * -1.44269504088896340736f);
    return __builtin_amdgcn_rcpf(1.0f + e);
}

// ---- projection segment: out[r,c] = dot(F[r,0:64], W[c, off:off+64]) ------
// 128 threads per row (c), 2 rows per 256-block per iter; W row cached in VGPRs.
__device__ __forceinline__ void proj_seg(
        const float* __restrict__ F, int rows,
        const float* __restrict__ W, int wcol_off,
        float* __restrict__ out, int b, int nb) {
    const int tid  = threadIdx.x;
    const int c    = tid & (CNUM - 1);
    const int half = tid >> 7;  // 0/1

    float w[EMB];
    const float4* Wr = (const float4*)(W + c * (2 * EMB) + wcol_off);
#pragma unroll
    for (int j = 0; j < 16; ++j) {
        float4 u = Wr[j];
        w[4*j+0] = u.x; w[4*j+1] = u.y; w[4*j+2] = u.z; w[4*j+3] = u.w;
    }

    for (int r = b * 2 + half; r < rows; r += nb * 2) {
        const float4* Fr = (const float4*)(F + r * EMB);  // broadcast across 128 thr
        float a0 = 0.f, a1 = 0.f, a2 = 0.f, a3 = 0.f;
#pragma unroll
        for (int j = 0; j < 16; ++j) {
            float4 u = Fr[j];
            a0 = fmaf(u.x, w[4*j+0], a0);
            a1 = fmaf(u.y, w[4*j+1], a1);
            a2 = fmaf(u.z, w[4*j+2], a2);
            a3 = fmaf(u.w, w[4*j+3], a3);
        }
        out[r * CNUM + c] = (a0 + a1) + (a2 + a3);  // coalesced
    }
}

// concept segment: half-block 0 -> CS (W_stu[:,64:]), half-block 1 -> CI
// (W_item[:,64:]); both halves share the same F row (broadcast).
__device__ __forceinline__ void proj_conc(
        const float* __restrict__ F,
        const float* __restrict__ W_stu, const float* __restrict__ W_item,
        float* __restrict__ CS, float* __restrict__ CI, int bb) {
    const int tid  = threadIdx.x;
    const int c    = tid & (CNUM - 1);
    const int half = tid >> 7;
    const float* W = half ? W_item : W_stu;
    float* O       = half ? CI : CS;

    float w[EMB];
    const float4* Wr = (const float4*)(W + c * (2 * EMB) + EMB);
#pragma unroll
    for (int j = 0; j < 16; ++j) {
        float4 u = Wr[j];
        w[4*j+0] = u.x; w[4*j+1] = u.y; w[4*j+2] = u.z; w[4*j+3] = u.w;
    }

    for (int r = bb; r < NCONC; r += CONC_BLKS) {
        const float4* Fr = (const float4*)(F + r * EMB);
        float a0 = 0.f, a1 = 0.f, a2 = 0.f, a3 = 0.f;
#pragma unroll
        for (int j = 0; j < 16; ++j) {
            float4 u = Fr[j];
            a0 = fmaf(u.x, w[4*j+0], a0);
            a1 = fmaf(u.y, w[4*j+1], a1);
            a2 = fmaf(u.z, w[4*j+2], a2);
            a3 = fmaf(u.w, w[4*j+3], a3);
        }
        O[r * CNUM + c] = (a0 + a1) + (a2 + a3);
    }
}

__global__ __launch_bounds__(256) void proj_all(
        const float* __restrict__ stuF, const float* __restrict__ itemF,
        const float* __restrict__ concF,
        const float* __restrict__ W_stu, const float* __restrict__ W_item,
        float* __restrict__ SP, float* __restrict__ IP,
        float* __restrict__ CS, float* __restrict__ CI) {
    const int b = blockIdx.x;
    if (b < STU_BLKS) {
        proj_seg(stuF, NSTU, W_stu, 0, SP, b, STU_BLKS);
    } else if (b < STU_BLKS + ITEM_BLKS) {
        proj_seg(itemF, NITEM, W_item, 0, IP, b - STU_BLKS, ITEM_BLKS);
    } else {
        proj_conc(concF, W_stu, W_item, CS, CI, b - STU_BLKS - ITEM_BLKS);
    }
}

// ---- edge phase: 4 edges per wave, 16 lanes per edge, lane owns 8 concepts -
// Amortizes index loads / addressing / butterfly / epilogue over 4 edges:
// ~4 shuffle-instrs per edge instead of 24, parallel epilogue.
__global__ __launch_bounds__(256) void edge_kernel(
        const int*  __restrict__ stu_idx,
        const int*  __restrict__ item_idx,
        const int4* __restrict__ conc_idx,   // (EDGES, 4) as int4
        const float* __restrict__ SP,        // (NSTU, 128)
        const float* __restrict__ IP,        // (NITEM, 128)
        const float* __restrict__ CS,        // (NCONC, 128)
        const float* __restrict__ CI,        // (NCONC, 128)
        const float* __restrict__ w_pred,
        const float* __restrict__ b_pred,
        float* __restrict__ out) {
    const int lane = threadIdx.x & 63;
    const int wv   = (blockIdx.x * blockDim.x + threadIdx.x) >> 6;  // global wave
    const int sub  = lane >> 4;      // edge within wave 0..3
    const int li   = lane & 15;      // lane within edge; owns c = li*8 .. li*8+7
    const int e    = wv * 4 + sub;   // grid sized exactly: e < EDGES

    const int s  = stu_idx[e];       // 16 lanes same address: broadcast
    const int it = item_idx[e];
    const int4 c4 = conc_idx[e];

    const float4* sp4 = (const float4*)(SP + s  * CNUM + li * 8);
    const float4* ip4 = (const float4*)(IP + it * CNUM + li * 8);
    const float4* wp4 = (const float4*)(w_pred + li * 8);
    const float4 spA = sp4[0], spB = sp4[1];
    const float4 ipA = ip4[0], ipB = ip4[1];
    const float4 wA  = wp4[0], wB  = wp4[1];
    const float  b   = b_pred[0];

    const int ck[4] = {c4.x, c4.y, c4.z, c4.w};
    float p[4];
#pragma unroll
    for (int k = 0; k < 4; ++k) {
        const float4* cs4 = (const float4*)(CS + ck[k] * CNUM + li * 8);
        const float4* ci4 = (const float4*)(CI + ck[k] * CNUM + li * 8);
        const float4 csA = cs4[0], csB = cs4[1];
        const float4 ciA = ci4[0], ciB = ci4[1];
        float a0 = 0.f, a1 = 0.f;
        a0 = fmaf(sigm(spA.x + csA.x) - sigm(ipA.x + ciA.x), wA.x, a0);
        a1 = fmaf(sigm(spA.y + csA.y) - sigm(ipA.y + ciA.y), wA.y, a1);
        a0 = fmaf(sigm(spA.z + csA.z) - sigm(ipA.z + ciA.z), wA.z, a0);
        a1 = fmaf(sigm(spA.w + csA.w) - sigm(ipA.w + ciA.w), wA.w, a1);
        a0 = fmaf(sigm(spB.x + csB.x) - sigm(ipB.x + ciB.x), wB.x, a0);
        a1 = fmaf(sigm(spB.y + csB.y) - sigm(ipB.y + ciB.y), wB.y, a1);
        a0 = fmaf(sigm(spB.z + csB.z) - sigm(ipB.z + ciB.z), wB.z, a0);
        a1 = fmaf(sigm(spB.w + csB.w) - sigm(ipB.w + ciB.w), wB.w, a1);
        p[k] = a0 + a1;
    }

    // reduce across the 16 lanes of each edge (xor masks 1,2,4,8 stay in-group)
#pragma unroll
    for (int m = 1; m <= 8; m <<= 1) {
        p[0] += __shfl_xor(p[0], m, 64);
        p[1] += __shfl_xor(p[1], m, 64);
        p[2] += __shfl_xor(p[2], m, 64);
        p[3] += __shfl_xor(p[3], m, 64);
    }

    // every lane of the group has the 4 k-sums; compute epilogue wave-wide,
    // one lane per edge stores (4 consecutive fp32 stores per wave).
    const float r = 0.25f * (sigm(p[0] + b) + sigm(p[1] + b) +
                             sigm(p[2] + b) + sigm(p[3] + b));
    if (li == 0) out[e] = r;
}

extern "C" void kernel_launch(void* const* d_in, const int* in_sizes, int n_in,
                              void* d_out, int out_size, void* d_ws, size_t ws_size,
                              hipStream_t stream) {
    const int* stu_idx  = (const int*)d_in[0];
    const int* item_idx = (const int*)d_in[1];
    const int* conc_idx = (const int*)d_in[2];
    const float* stu_fusion     = (const float*)d_in[3];
    const float* item_fusion    = (const float*)d_in[4];
    const float* concept_fusion = (const float*)d_in[5];
    const float* W_stu          = (const float*)d_in[6];
    const float* W_item         = (const float*)d_in[7];
    const float* w_pred         = (const float*)d_in[8];
    const float* b_pred         = (const float*)d_in[9];
    float* out = (float*)d_out;

    float* SP = (float*)d_ws + SP_OFF;
    float* IP = (float*)d_ws + IP_OFF;
    float* CS = (float*)d_ws + CS_OFF;
    float* CI = (float*)d_ws + CI_OFF;

    proj_all<<<TOTAL_BLKS, 256, 0, stream>>>(
        stu_fusion, item_fusion, concept_fusion, W_stu, W_item, SP, IP, CS, CI);

    // 16 edges per 256-block: 250000 / 16 = 15625 blocks exactly
    edge_kernel<<<EDGES / 16, 256, 0, stream>>>(
        stu_idx, item_idx, (const int4*)conc_idx,
        SP, IP, CS, CI, w_pred, b_pred, out);
}

// Round 4
// 197.611 us; speedup vs baseline: 1.4270x; 1.3191x over previous
//
#include <hip/hip_runtime.h>
#include <hip/hip_bf16.h>

// All float tensors are fp32 (proven R1/R2). Output fp32.
constexpr int EDGES = 250000;
constexpr int EMB   = 64;
constexpr int CNUM  = 128;
constexpr int NSTU  = 10000;
constexpr int NITEM = 50000;
constexpr int NCONC = 2048;

// workspace layout (fp32): SP | IP | CS | CI   (tables pre-scaled by -log2e)
constexpr size_t SP_OFF = 0;
constexpr size_t IP_OFF = SP_OFF + (size_t)NSTU  * CNUM;
constexpr size_t CS_OFF = IP_OFF + (size_t)NITEM * CNUM;
constexpr size_t CI_OFF = CS_OFF + (size_t)NCONC * CNUM;

// proj_all block segmentation (~13 rows per 128-thread half everywhere)
constexpr int STU_BLKS  = 384;
constexpr int ITEM_BLKS = 1920;
constexpr int CONC_BLKS = 96;
constexpr int TOTAL_BLKS = STU_BLKS + ITEM_BLKS + CONC_BLKS;

constexpr float NEG_LOG2E = -1.44269504088896340736f;

// sigmoid with pre-scaled argument: xs = -x*log2e already applied
__device__ __forceinline__ float sigm_pre(float xs) {
    return __builtin_amdgcn_rcpf(1.0f + __builtin_amdgcn_exp2f(xs));
}
// full sigmoid (epilogue only)
__device__ __forceinline__ float sigm(float x) {
    return sigm_pre(x * NEG_LOG2E);
}

// ---- projection: out[r,c] = -log2e * dot(F[r,0:64], W[c, off:off+64]) -----
// W row cached in 64 VGPRs; F row fetched via SCALAR loads (row index is
// wave-uniform -> readfirstlane lets the compiler emit s_load_dwordx16, so
// each F element feeds v_fmac as an SGPR operand: zero VMEM in the row loop).
__device__ __forceinline__ void proj_seg(
        const float* __restrict__ F, int rows,
        const float* __restrict__ W, int wcol_off,
        float* __restrict__ out, int b, int nb) {
    const int c    = threadIdx.x & (CNUM - 1);
    const int half = threadIdx.x >> 7;  // wave-uniform (waves 0,1 -> 0; 2,3 -> 1)

    float w[EMB];
    const float4* Wr = (const float4*)(W + c * (2 * EMB) + wcol_off);
#pragma unroll
    for (int j = 0; j < 16; ++j) {
        float4 u = Wr[j];
        w[4*j+0] = u.x; w[4*j+1] = u.y; w[4*j+2] = u.z; w[4*j+3] = u.w;
    }

    for (int r = b * 2 + half; r < rows; r += nb * 2) {
        const float* __restrict__ Fr =
            F + (size_t)__builtin_amdgcn_readfirstlane(r) * EMB;
        float a0 = 0.f, a1 = 0.f, a2 = 0.f, a3 = 0.f;
#pragma unroll
        for (int j = 0; j < 16; ++j) {
            a0 = fmaf(Fr[4*j+0], w[4*j+0], a0);
            a1 = fmaf(Fr[4*j+1], w[4*j+1], a1);
            a2 = fmaf(Fr[4*j+2], w[4*j+2], a2);
            a3 = fmaf(Fr[4*j+3], w[4*j+3], a3);
        }
        out[r * CNUM + c] = ((a0 + a1) + (a2 + a3)) * NEG_LOG2E;  // coalesced
    }
}

// concept segment: half 0 -> CS (W_stu[:,64:]), half 1 -> CI (W_item[:,64:])
__device__ __forceinline__ void proj_conc(
        const float* __restrict__ F,
        const float* __restrict__ W_stu, const float* __restrict__ W_item,
        float* __restrict__ CS, float* __restrict__ CI, int bb) {
    const int c    = threadIdx.x & (CNUM - 1);
    const int half = threadIdx.x >> 7;
    const float* __restrict__ W = half ? W_item : W_stu;
    float* __restrict__ O       = half ? CI : CS;

    float w[EMB];
    const float4* Wr = (const float4*)(W + c * (2 * EMB) + EMB);
#pragma unroll
    for (int j = 0; j < 16; ++j) {
        float4 u = Wr[j];
        w[4*j+0] = u.x; w[4*j+1] = u.y; w[4*j+2] = u.z; w[4*j+3] = u.w;
    }

    for (int r = bb; r < NCONC; r += CONC_BLKS) {
        const float* __restrict__ Fr =
            F + (size_t)__builtin_amdgcn_readfirstlane(r) * EMB;
        float a0 = 0.f, a1 = 0.f, a2 = 0.f, a3 = 0.f;
#pragma unroll
        for (int j = 0; j < 16; ++j) {
            a0 = fmaf(Fr[4*j+0], w[4*j+0], a0);
            a1 = fmaf(Fr[4*j+1], w[4*j+1], a1);
            a2 = fmaf(Fr[4*j+2], w[4*j+2], a2);
            a3 = fmaf(Fr[4*j+3], w[4*j+3], a3);
        }
        O[r * CNUM + c] = ((a0 + a1) + (a2 + a3)) * NEG_LOG2E;
    }
}

__global__ __launch_bounds__(256) void proj_all(
        const float* __restrict__ stuF, const float* __restrict__ itemF,
        const float* __restrict__ concF,
        const float* __restrict__ W_stu, const float* __restrict__ W_item,
        float* __restrict__ SP, float* __restrict__ IP,
        float* __restrict__ CS, float* __restrict__ CI) {
    const int b = blockIdx.x;
    if (b < STU_BLKS) {
        proj_seg(stuF, NSTU, W_stu, 0, SP, b, STU_BLKS);
    } else if (b < STU_BLKS + ITEM_BLKS) {
        proj_seg(itemF, NITEM, W_item, 0, IP, b - STU_BLKS, ITEM_BLKS);
    } else {
        proj_conc(concF, W_stu, W_item, CS, CI, b - STU_BLKS - ITEM_BLKS);
    }
}

// ---- edge phase: 4 edges/wave, 16 lanes/edge, lane owns 8 channels --------
// Tables arrive pre-scaled by -log2e, so each inner sigmoid is add+exp2+add+rcp
// (no multiply).
__global__ __launch_bounds__(256) void edge_kernel(
        const int*  __restrict__ stu_idx,
        const int*  __restrict__ item_idx,
        const int4* __restrict__ conc_idx,
        const float* __restrict__ SP,
        const float* __restrict__ IP,
        const float* __restrict__ CS,
        const float* __restrict__ CI,
        const float* __restrict__ w_pred,
        const float* __restrict__ b_pred,
        float* __restrict__ out) {
    const int lane = threadIdx.x & 63;
    const int wv   = (blockIdx.x * blockDim.x + threadIdx.x) >> 6;
    const int sub  = lane >> 4;      // edge within wave 0..3
    const int li   = lane & 15;      // lane within edge; owns ch li*8..li*8+7
    const int e    = wv * 4 + sub;   // grid sized exactly

    const int s  = stu_idx[e];
    const int it = item_idx[e];
    const int4 c4 = conc_idx[e];

    const float4* sp4 = (const float4*)(SP + (size_t)s  * CNUM + li * 8);
    const float4* ip4 = (const float4*)(IP + (size_t)it * CNUM + li * 8);
    const float4* wp4 = (const float4*)(w_pred + li * 8);
    const float4 spA = sp4[0], spB = sp4[1];
    const float4 ipA = ip4[0], ipB = ip4[1];
    const float4 wA  = wp4[0], wB  = wp4[1];
    const float  b   = b_pred[0];

    const int ck[4] = {c4.x, c4.y, c4.z, c4.w};
    float p[4];
#pragma unroll
    for (int k = 0; k < 4; ++k) {
        const float4* cs4 = (const float4*)(CS + (size_t)ck[k] * CNUM + li * 8);
        const float4* ci4 = (const float4*)(CI + (size_t)ck[k] * CNUM + li * 8);
        const float4 csA = cs4[0], csB = cs4[1];
        const float4 ciA = ci4[0], ciB = ci4[1];
        float a0 = 0.f, a1 = 0.f;
        a0 = fmaf(sigm_pre(spA.x + csA.x) - sigm_pre(ipA.x + ciA.x), wA.x, a0);
        a1 = fmaf(sigm_pre(spA.y + csA.y) - sigm_pre(ipA.y + ciA.y), wA.y, a1);
        a0 = fmaf(sigm_pre(spA.z + csA.z) - sigm_pre(ipA.z + ciA.z), wA.z, a0);
        a1 = fmaf(sigm_pre(spA.w + csA.w) - sigm_pre(ipA.w + ciA.w), wA.w, a1);
        a0 = fmaf(sigm_pre(spB.x + csB.x) - sigm_pre(ipB.x + ciB.x), wB.x, a0);
        a1 = fmaf(sigm_pre(spB.y + csB.y) - sigm_pre(ipB.y + ciB.y), wB.y, a1);
        a0 = fmaf(sigm_pre(spB.z + csB.z) - sigm_pre(ipB.z + ciB.z), wB.z, a0);
        a1 = fmaf(sigm_pre(spB.w + csB.w) - sigm_pre(ipB.w + ciB.w), wB.w, a1);
        p[k] = a0 + a1;
    }

#pragma unroll
    for (int m = 1; m <= 8; m <<= 1) {
        p[0] += __shfl_xor(p[0], m, 64);
        p[1] += __shfl_xor(p[1], m, 64);
        p[2] += __shfl_xor(p[2], m, 64);
        p[3] += __shfl_xor(p[3], m, 64);
    }

    const float r = 0.25f * (sigm(p[0] + b) + sigm(p[1] + b) +
                             sigm(p[2] + b) + sigm(p[3] + b));
    if (li == 0) out[e] = r;
}

extern "C" void kernel_launch(void* const* d_in, const int* in_sizes, int n_in,
                              void* d_out, int out_size, void* d_ws, size_t ws_size,
                              hipStream_t stream) {
    const int* stu_idx  = (const int*)d_in[0];
    const int* item_idx = (const int*)d_in[1];
    const int* conc_idx = (const int*)d_in[2];
    const float* stu_fusion     = (const float*)d_in[3];
    const float* item_fusion    = (const float*)d_in[4];
    const float* concept_fusion = (const float*)d_in[5];
    const float* W_stu          = (const float*)d_in[6];
    const float* W_item         = (const float*)d_in[7];
    const float* w_pred         = (const float*)d_in[8];
    const float* b_pred         = (const float*)d_in[9];
    float* out = (float*)d_out;

    float* SP = (float*)d_ws + SP_OFF;
    float* IP = (float*)d_ws + IP_OFF;
    float* CS = (float*)d_ws + CS_OFF;
    float* CI = (float*)d_ws + CI_OFF;

    proj_all<<<TOTAL_BLKS, 256, 0, stream>>>(
        stu_fusion, item_fusion, concept_fusion, W_stu, W_item, SP, IP, CS, CI);

    edge_kernel<<<EDGES / 16, 256, 0, stream>>>(
        stu_idx, item_idx, (const int4*)conc_idx,
        SP, IP, CS, CI, w_pred, b_pred, out);
}